// Round 10
// baseline (2199.200 us; speedup 1.0000x reference)
//
#include <hip/hip_runtime.h>

// CommAgent fully-fused pipeline for MI355X (gfx950), bf16 MFMA throughout.
// ROWS=65536, INPUT=512, H=256, NA=32, 4 comm steps, N_ACTIONS=16.
//
// Round-10: barrier-domain multiplication. r9 falsified the window-latency
// theory (33% fewer gemm passes = 0 gain); the stall is wave starvation:
// 4 waves/SIMD from only 2 barrier domains. This round: 32-row blocks
// (one agent group), 256 threads (4 waves), grid 2048, LDS 34.6 KB ->
// 4 blocks/CU -> each SIMD hosts 4 waves from 4 INDEPENDENT blocks.
// GRU in 16-row halves (NMB=1); rp/zp 32 regs; keep unroll 2 (r8 fix).

typedef __attribute__((ext_vector_type(8))) short frag8;   // 8 bf16 (4 VGPRs)
typedef __attribute__((ext_vector_type(4))) float facc4;   // MFMA C/D
typedef __attribute__((ext_vector_type(4))) float f32x4;   // NT-loadable float4

__device__ __forceinline__ unsigned short f2bf(float f){
    unsigned u = __builtin_bit_cast(unsigned, f);
    u += 0x7fffu + ((u >> 16) & 1u);            // RNE
    return (unsigned short)(u >> 16);
}
__device__ __forceinline__ float bf2f(unsigned short h){
    unsigned u = ((unsigned)h) << 16;
    return __builtin_bit_cast(float, u);
}
__device__ __forceinline__ unsigned pk2(float a, float b){
    return (unsigned)f2bf(a) | ((unsigned)f2bf(b) << 16);
}
__device__ __forceinline__ float sigm(float x){ return 1.0f / (1.0f + __expf(-x)); }
__device__ __forceinline__ float tanh_(float x){ return 2.0f / (1.0f + __expf(-2.0f*x)) - 1.0f; }

__device__ __forceinline__ facc4 mfma16(frag8 a, frag8 b, facc4 c){
    return __builtin_amdgcn_mfma_f32_16x16x32_bf16(a, b, c, 0, 0, 0);
}
// XOR-swizzled LDS index (16B-chunk granularity), ld=256 shorts
__device__ __forceinline__ int swz(int row, int col, int ld){
    return row*ld + ((((col >> 3) ^ (row & 7)) << 3) | (col & 7));
}
__device__ __forceinline__ void z2(facc4 (&x)[2]){
    x[0] = (facc4){0.f,0.f,0.f,0.f}; x[1] = (facc4){0.f,0.f,0.f,0.f};
}

// ---- general gemm (phase X): acc[NMB][NTT] += A_lds @ W[nrow0..]^T ----
// unroll 2: bound the VMEM prefetch window (round-8 fix; do not remove).
template<int NMB, int NTT>
__device__ __forceinline__ void gemm_bt(facc4 (&acc)[NMB][NTT],
    const unsigned short* Al, const int ld, const int mb0,
    const unsigned short* __restrict__ W, const int nrow0, const int K, const int wK)
{
    const int lane = threadIdx.x & 63;
    const int r16  = lane & 15;
    const int q8   = (lane >> 4) << 3;
    int rowbase[NMB], rx[NMB];
    #pragma unroll
    for (int mb = 0; mb < NMB; ++mb){
        int row = (mb0 + mb)*16 + r16;
        rowbase[mb] = row * ld;
        rx[mb] = row & 7;
    }
    const unsigned short* wbase = W + (size_t)(nrow0 + r16) * wK + q8;
    #pragma unroll 2
    for (int k0 = 0; k0 < K; k0 += 32){
        const int c8 = (k0 + q8) >> 3;
        frag8 a[NMB];
        #pragma unroll
        for (int mb = 0; mb < NMB; ++mb)
            a[mb] = *(const frag8*)(Al + rowbase[mb] + ((c8 ^ rx[mb]) << 3));
        #pragma unroll
        for (int tt = 0; tt < NTT; ++tt){
            frag8 b = *(const frag8*)(wbase + tt*16*wK + k0);
            #pragma unroll
            for (int mb = 0; mb < NMB; ++mb)
                acc[mb][tt] = mfma16(a[mb], b, acc[mb][tt]);
        }
    }
}

// ---- NMB=1 n-gate gemm: acc[2] += A_lds(rows row0..row0+15) @ W^T ----
__device__ __forceinline__ void gemm_bt1(facc4 (&acc)[2],
    const unsigned short* Al, const int row0,
    const unsigned short* __restrict__ W, const int nrow0, const int wK)
{
    const int lane = threadIdx.x & 63;
    const int r16  = lane & 15;
    const int q8   = (lane >> 4) << 3;
    const int row  = row0 + r16;
    const int rowbase = row * 256, rx = row & 7;
    const unsigned short* wbase = W + (size_t)(nrow0 + r16) * wK + q8;
    #pragma unroll 2
    for (int k0 = 0; k0 < 256; k0 += 32){
        const int c8 = (k0 + q8) >> 3;
        frag8 a = *(const frag8*)(Al + rowbase + ((c8 ^ rx) << 3));
        #pragma unroll
        for (int tt = 0; tt < 2; ++tt){
            frag8 b = *(const frag8*)(wbase + tt*16*wK + k0);
            acc[tt] = mfma16(a, b, acc[tt]);
        }
    }
}

// ---- NMB=1 fused r+z gemm (W rows 0..255 = r, 256..511 = z) ----
__device__ __forceinline__ void gemm_rz1(facc4 (&accr)[2], facc4 (&accz)[2],
    const unsigned short* Al, const int row0,
    const unsigned short* __restrict__ W, const int nrowr, const int wK)
{
    const int lane = threadIdx.x & 63;
    const int r16  = lane & 15;
    const int q8   = (lane >> 4) << 3;
    const int row  = row0 + r16;
    const int rowbase = row * 256, rx = row & 7;
    const unsigned short* wr = W + (size_t)(nrowr + r16) * wK + q8;
    const unsigned short* wz = wr + (size_t)256 * wK;
    #pragma unroll 2
    for (int k0 = 0; k0 < 256; k0 += 32){
        const int c8 = (k0 + q8) >> 3;
        frag8 a = *(const frag8*)(Al + rowbase + ((c8 ^ rx) << 3));
        #pragma unroll
        for (int tt = 0; tt < 2; ++tt){
            frag8 br = *(const frag8*)(wr + tt*16*wK + k0);
            frag8 bz = *(const frag8*)(wz + tt*16*wK + k0);
            accr[tt] = mfma16(a, br, accr[tt]);
            accz[tt] = mfma16(a, bz, accz[tt]);
        }
    }
}

// stage 32 rows x 256 cols of f32 (row stride sld) -> swizzled bf16 LDS (ld=256)
// 256 threads; non-temporal loads (pure stream)
__device__ __forceinline__ void stage_f32s(unsigned short* dst, const float* src, int sld){
    int t = threadIdx.x;
    #pragma unroll
    for (int it = 0; it < 4; ++it){
        int idx = it*256 + t;                  // 1024 chunks of 8 shorts
        int row = idx >> 5, ch = idx & 31;
        const f32x4* s = (const f32x4*)(src + (size_t)row*sld + (ch << 3));
        f32x4 a = __builtin_nontemporal_load(s);
        f32x4 b = __builtin_nontemporal_load(s + 1);
        uint4 o; o.x = pk2(a.x,a.y); o.y = pk2(a.z,a.w); o.z = pk2(b.x,b.y); o.w = pk2(b.z,b.w);
        *(uint4*)(dst + row*256 + ((ch ^ (row & 7)) << 3)) = o;
    }
}

// ---- weight f32->bf16 conversion (segments packed contiguously in ws) ----
__global__ void k_prep(const float* __restrict__ s0, const float* __restrict__ s1,
                       const float* __restrict__ s2, const float* __restrict__ s3,
                       const float* __restrict__ s4, const float* __restrict__ s5,
                       unsigned short* __restrict__ dst)
{
    int idx = (blockIdx.x*256 + threadIdx.x) * 4;   // 921600 elems total
    const float* src;
    if      (idx < 131072) src = s0 + idx;
    else if (idx < 327680) src = s1 + (idx - 131072);
    else if (idx < 524288) src = s2 + (idx - 327680);
    else if (idx < 720896) src = s3 + (idx - 524288);
    else if (idx < 917504) src = s4 + (idx - 720896);
    else                   src = s5 + (idx - 917504);
    float4 v = *(const float4*)src;
    uint2 o; o.x = pk2(v.x, v.y); o.y = pk2(v.z, v.w);
    *(uint2*)(dst + idx) = o;
}

// ---- GRU for ONE 16-row half (rows mbh*16..+15). 256 threads, 4 waves x
// 64 cols (2 tth sub-passes of 32). gi from A (h written back into A),
// gh from B. One internal barrier between n-gemm reads and h writes.
template<bool WRITE_F32>
__device__ __forceinline__ void gru_half(const int mbh,
    unsigned short* A, const unsigned short* B,      // LDS, ld=256 swizzled
    const unsigned short* __restrict__ Wih, const unsigned short* __restrict__ Whh,
    const float* __restrict__ bih, const float* __restrict__ bhh,
    int base, float* __restrict__ out32)
{
    const int lane = threadIdx.x & 63, wv = threadIdx.x >> 6;
    const int r16 = lane & 15, q4 = (lane >> 4) << 2;
    const int row0 = mbh*16;
    unsigned rp[2][2][2], zp[2][2][2];    // [tth][tt][pair]
    #pragma unroll
    for (int tth = 0; tth < 2; ++tth){
        facc4 accr[2], accz[2];
        z2(accr); z2(accz);
        gemm_rz1(accr, accz, A, row0, Wih, wv*64 + tth*32, 256);
        gemm_rz1(accr, accz, B, row0, Whh, wv*64 + tth*32, 256);
        #pragma unroll
        for (int tt = 0; tt < 2; ++tt){
            int col = wv*64 + tth*32 + tt*16 + r16;
            float bsr = bih[col] + bhh[col];
            float bsz = bih[256+col] + bhh[256+col];
            rp[tth][tt][0] = pk2(sigm(accr[tt][0]+bsr), sigm(accr[tt][1]+bsr));
            rp[tth][tt][1] = pk2(sigm(accr[tt][2]+bsr), sigm(accr[tt][3]+bsr));
            zp[tth][tt][0] = pk2(sigm(accz[tt][0]+bsz), sigm(accz[tt][1]+bsz));
            zp[tth][tt][1] = pk2(sigm(accz[tt][2]+bsz), sigm(accz[tt][3]+bsz));
        }
    }
    // n gemms for both tth, then one barrier, then epilogue + writes
    facc4 ai[2][2], ah[2][2];             // [tth][tt]
    z2(ai[0]); z2(ai[1]); z2(ah[0]); z2(ah[1]);
    #pragma unroll
    for (int tth = 0; tth < 2; ++tth){
        gemm_bt1(ai[tth], A, row0, Wih, 512 + wv*64 + tth*32, 256);
        gemm_bt1(ah[tth], B, row0, Whh, 512 + wv*64 + tth*32, 256);
    }
    __syncthreads();    // all waves done reading this half's A rows
    #pragma unroll
    for (int tth = 0; tth < 2; ++tth){
        #pragma unroll
        for (int tt = 0; tt < 2; ++tt){
            int col = wv*64 + tth*32 + tt*16 + r16;
            float bi = bih[512+col], bh2 = bhh[512+col];
            #pragma unroll
            for (int k = 0; k < 4; ++k){
                int rloc = row0 + q4 + k;
                float iv = ai[tth][tt][k] + bi;
                float hv = ah[tth][tt][k] + bh2;
                float r = bf2f((unsigned short)(rp[tth][tt][k>>1] >> ((k&1)*16)));
                float z = bf2f((unsigned short)(zp[tth][tt][k>>1] >> ((k&1)*16)));
                float n = tanh_(iv + r*hv);
                float hprev = bf2f(B[swz(rloc, col, 256)]);
                float h = (1.f - z)*n + z*hprev;
                if (WRITE_F32)
                    __builtin_nontemporal_store(h, &out32[(size_t)(base + rloc)*256 + col]);
                A[swz(rloc, col, 256)] = f2bf(h);
            }
        }
    }
}

// c = (NB @ h) * invn for one 32-agent group; h in Hl, out to Cl (swizzled)
__device__ __forceinline__ void comm_c(const unsigned short* Hl, unsigned short* Cl,
                                       const unsigned short* NBl, const float* invl)
{
    const int lane = threadIdx.x & 63, wv = threadIdx.x >> 6;
    const int r16 = lane & 15, q8 = (lane >> 4) << 3, q4 = (lane >> 4) << 2;
    frag8 a[2];
    #pragma unroll
    for (int mb = 0; mb < 2; ++mb)
        a[mb] = *(const frag8*)(NBl + (mb*16 + r16)*40 + q8);
    #pragma unroll
    for (int tth = 0; tth < 2; ++tth){
        facc4 acc[2][2];                  // [mb][tt]
        z2(acc[0]); z2(acc[1]);
        #pragma unroll
        for (int tt = 0; tt < 2; ++tt){
            int col = wv*64 + tth*32 + tt*16 + r16;
            int cc = col >> 3, c7 = col & 7;
            frag8 b;
            #pragma unroll
            for (int j = 0; j < 8; ++j){
                int kr = q8 + j;          // agent rows 0..31
                b[j] = (short)Hl[kr*256 + (((cc ^ (kr & 7)) << 3) | c7)];
            }
            acc[0][tt] = mfma16(a[0], b, acc[0][tt]);
            acc[1][tt] = mfma16(a[1], b, acc[1][tt]);
        }
        #pragma unroll
        for (int mb = 0; mb < 2; ++mb){
            #pragma unroll
            for (int k = 0; k < 4; ++k){
                int rloc = mb*16 + q4 + k;
                float inv = invl[rloc];
                #pragma unroll
                for (int tt = 0; tt < 2; ++tt){
                    int col = wv*64 + tth*32 + tt*16 + r16;
                    Cl[swz(rloc, col, 256)] = f2bf(acc[mb][tt][k] * inv);
                }
            }
        }
    }
}

// ---- the whole pipeline, 32 rows (1 agent group) per block, 256 threads ----
__global__ __launch_bounds__(256) void k_fused(
    const float* __restrict__ inputs, const float* __restrict__ h0,
    const unsigned short* __restrict__ W1c, const float* __restrict__ b1,
    const unsigned short* __restrict__ rWih, const unsigned short* __restrict__ rWhh,
    const float* __restrict__ rbih, const float* __restrict__ rbhh,
    const unsigned short* __restrict__ cWih, const unsigned short* __restrict__ cWhh,
    const float* __restrict__ cbih, const float* __restrict__ cbhh,
    const unsigned short* __restrict__ W2c, const float* __restrict__ b2,
    float* __restrict__ qout, float* __restrict__ hrnn)
{
    __shared__ unsigned short A[32*256];     // 16 KB: X, then h
    __shared__ unsigned short B[32*256];     // 16 KB: input halves, h0, then C
    __shared__ unsigned short NBl[32*40];    // 2.5 KB
    __shared__ float invl[32];
    const int base = blockIdx.x * 32;
    const int lane = threadIdx.x & 63, wv = threadIdx.x >> 6;
    const int r16 = lane & 15, q8 = (lane >> 4) << 3, q4 = (lane >> 4) << 2;

    // ================= phase X: x = relu(inp @ W1^T + b1) -> A =================
    {
        facc4 xacc[2][2][2];                 // [tth][mb][tt]
        #pragma unroll
        for (int tth = 0; tth < 2; ++tth){ z2(xacc[tth][0]); z2(xacc[tth][1]); }
        // K-half 1 (input cols 0..255)
        stage_f32s(B, inputs + (size_t)base*512, 512);
        __syncthreads();
        #pragma unroll
        for (int tth = 0; tth < 2; ++tth)
            gemm_bt<2,2>(xacc[tth], B, 256, 0, W1c, wv*64 + tth*32, 256, 512);
        __syncthreads();                     // all reads of B done
        // K-half 2 (input cols 256..511)
        stage_f32s(B, inputs + (size_t)base*512 + 256, 512);
        __syncthreads();
        // neighbor extraction: global cols 260+8k -> local col 4+8k -> chunk k, sub 4
        if (threadIdx.x < 32){
            int row = threadIdx.x;           // agent i == row (base % 32 == 0)
            int rx = row & 7;
            unsigned short* nbrow = NBl + row*40;
            float s = 0.f;
            nbrow[row] = 0;
            #pragma unroll
            for (int k = 0; k < 31; ++k){
                unsigned short v = B[row*256 + (((k ^ rx) << 3) | 4)];
                s += bf2f(v);
                nbrow[k + (k >= row)] = v;
            }
            invl[row] = 1.0f / s;
        }
        #pragma unroll
        for (int tth = 0; tth < 2; ++tth)
            gemm_bt<2,2>(xacc[tth], B, 256, 0, W1c + 256, wv*64 + tth*32, 256, 512);
        // write X -> A (A not read by anyone yet)
        #pragma unroll
        for (int tth = 0; tth < 2; ++tth){
            #pragma unroll
            for (int tt = 0; tt < 2; ++tt){
                int col = wv*64 + tth*32 + tt*16 + r16;
                float bias = b1[col];
                #pragma unroll
                for (int mb = 0; mb < 2; ++mb){
                    #pragma unroll
                    for (int k = 0; k < 4; ++k){
                        float v = fmaxf(xacc[tth][mb][tt][k] + bias, 0.f);
                        A[swz(mb*16 + q4 + k, col, 256)] = f2bf(v);
                    }
                }
            }
        }
    }
    __syncthreads();                // X in A complete; all reads of B done

    // ================= rnn GRU: h1 = GRU(X, h0) -> A =================
    stage_f32s(B, h0 + (size_t)base*256, 256);
    __syncthreads();
    gru_half<true>(0, A, B, rWih, rWhh, rbih, rbhh, base, hrnn);
    gru_half<true>(1, A, B, rWih, rWhh, rbih, rbhh, base, hrnn);
    __syncthreads();

    // ================= 4 comm steps, fully in LDS =================
    #pragma unroll 1
    for (int step = 0; step < 4; ++step){
        comm_c(A, B, NBl, invl);    // reads A, writes c -> B
        __syncthreads();
        gru_half<false>(0, A, B, cWih, cWhh, cbih, cbhh, base, nullptr);
        gru_half<false>(1, A, B, cWih, cWhh, cbih, cbhh, base, nullptr);
        __syncthreads();
    }

    // ================= q = h @ W2^T + b2 (N=16, one n-tile) =================
    if (wv < 2){
        facc4 qa = (facc4){0.f,0.f,0.f,0.f};
        int rowl = wv*16 + r16;
        const int rb = rowl*256, rx = rowl & 7;
        const unsigned short* brow = W2c + (size_t)r16*256 + q8;
        #pragma unroll
        for (int k0 = 0; k0 < 256; k0 += 32){
            int c8 = (k0 + q8) >> 3;
            frag8 af = *(const frag8*)(A + rb + ((c8 ^ rx) << 3));
            frag8 bf = *(const frag8*)(brow + k0);
            qa = mfma16(af, bf, qa);
        }
        float bias = b2[r16];
        #pragma unroll
        for (int k = 0; k < 4; ++k)
            __builtin_nontemporal_store(qa[k] + bias,
                &qout[(size_t)(base + wv*16 + q4 + k)*16 + r16]);
    }
}

extern "C" void kernel_launch(void* const* d_in, const int* in_sizes, int n_in,
                              void* d_out, int out_size, void* d_ws, size_t ws_size,
                              hipStream_t stream)
{
    const float* inputs = (const float*)d_in[0];
    const float* h0     = (const float*)d_in[1];
    const float* W1     = (const float*)d_in[2];
    const float* b1     = (const float*)d_in[3];
    const float* rWih   = (const float*)d_in[4];
    const float* rWhh   = (const float*)d_in[5];
    const float* rbih   = (const float*)d_in[6];
    const float* rbhh   = (const float*)d_in[7];
    const float* cWih   = (const float*)d_in[8];
    const float* cWhh   = (const float*)d_in[9];
    const float* cbih   = (const float*)d_in[10];
    const float* cbhh   = (const float*)d_in[11];
    const float* W2     = (const float*)d_in[12];
    const float* b2     = (const float*)d_in[13];

    float* qout = (float*)d_out;                    // 65536 x 16
    float* hrnn = qout + (size_t)65536*16;          // 65536 x 256

    // ws: bf16 weights only (921600 elems), segments packed contiguously
    unsigned short* wsb   = (unsigned short*)d_ws;
    unsigned short* W1c   = wsb;
    unsigned short* rWihc = wsb + 131072;
    unsigned short* rWhhc = wsb + 327680;
    unsigned short* cWihc = wsb + 524288;
    unsigned short* cWhhc = wsb + 720896;
    unsigned short* W2c   = wsb + 917504;

    k_prep <<<900, dim3(256), 0, stream>>>(W1, rWih, rWhh, cWih, cWhh, W2, wsb);
    k_fused<<<2048, dim3(256), 0, stream>>>(inputs, h0, W1c, b1,
                                            rWihc, rWhhc, rbih, rbhh,
                                            cWihc, cWhhc, cbih, cbhh,
                                            W2c, b2, qout, hrnn);
}

// Round 11
// 939.056 us; speedup vs baseline: 2.3419x; 2.3419x over previous
//
#include <hip/hip_runtime.h>

// CommAgent fully-fused pipeline for MI355X (gfx950), bf16 MFMA throughout.
// ROWS=65536, INPUT=512, H=256, NA=32, 4 comm steps, N_ACTIONS=16.
//
// Round-11: 3-buffer rotation (A/B/C = h / c / h-out), barrier-free GRU.
//  - GRU writes h' to a third buffer -> ZERO intra-GRU barriers (was 2),
//    2 barriers per comm step, ~15 total (was ~25). Waves decoupled.
//  - Each wave processes all 64 rows (NMB=4): 2x MFMA per weight fragment,
//    4 gemm passes/GRU instead of 8.
//  - LDS 104 KB -> 1 block/CU -> 2 waves/SIMD -> VGPR budget 256. With
//    unroll 4, in-flight loads (~128 regs) + acc fit in ~220 VGPRs: L2
//    latency (250cy) hidden by per-group MFMA time (~310cy) within a wave.
//  - h0 staging issued at kernel start, hides under the whole X phase.
// Keep: swizzled LDS, NT stream loads/stores, unroll-capped gemms (r8 fix).

typedef __attribute__((ext_vector_type(8))) short frag8;   // 8 bf16 (4 VGPRs)
typedef __attribute__((ext_vector_type(4))) float facc4;   // MFMA C/D
typedef __attribute__((ext_vector_type(4))) float f32x4;   // NT-loadable float4

__device__ __forceinline__ unsigned short f2bf(float f){
    unsigned u = __builtin_bit_cast(unsigned, f);
    u += 0x7fffu + ((u >> 16) & 1u);            // RNE
    return (unsigned short)(u >> 16);
}
__device__ __forceinline__ float bf2f(unsigned short h){
    unsigned u = ((unsigned)h) << 16;
    return __builtin_bit_cast(float, u);
}
__device__ __forceinline__ unsigned pk2(float a, float b){
    return (unsigned)f2bf(a) | ((unsigned)f2bf(b) << 16);
}
__device__ __forceinline__ float sigm(float x){ return 1.0f / (1.0f + __expf(-x)); }
__device__ __forceinline__ float tanh_(float x){ return 2.0f / (1.0f + __expf(-2.0f*x)) - 1.0f; }

__device__ __forceinline__ facc4 mfma16(frag8 a, frag8 b, facc4 c){
    return __builtin_amdgcn_mfma_f32_16x16x32_bf16(a, b, c, 0, 0, 0);
}
__device__ __forceinline__ void zacc(facc4* p, int n){
    #pragma unroll
    for (int i = 0; i < 16; ++i) { if (i < n) p[i] = (facc4){0.f,0.f,0.f,0.f}; }
}
// XOR-swizzled LDS index (16B-chunk granularity), ld=256 shorts
__device__ __forceinline__ int swz(int row, int col, int ld){
    return row*ld + ((((col >> 3) ^ (row & 7)) << 3) | (col & 7));
}

// acc[NMB][NTT] += A_lds(rows mb0*16..) @ W[nrow0 + tt*16 rows, K]^T
// unroll 4: deep enough to hide L2 latency in-wave at the 256-VGPR budget,
// shallow enough not to balloon past it (r8 lesson: NEVER full-unroll).
template<int NMB, int NTT>
__device__ __forceinline__ void gemm_bt(facc4 (&acc)[NMB][NTT],
    const unsigned short* Al, const int ld, const int mb0,
    const unsigned short* __restrict__ W, const int nrow0, const int K, const int wK)
{
    const int lane = threadIdx.x & 63;
    const int r16  = lane & 15;
    const int q8   = (lane >> 4) << 3;
    int rowbase[NMB], rx[NMB];
    #pragma unroll
    for (int mb = 0; mb < NMB; ++mb){
        int row = (mb0 + mb)*16 + r16;
        rowbase[mb] = row * ld;
        rx[mb] = row & 7;
    }
    const unsigned short* wbase = W + (size_t)(nrow0 + r16) * wK + q8;
    #pragma unroll 4
    for (int k0 = 0; k0 < K; k0 += 32){
        const int c8 = (k0 + q8) >> 3;
        frag8 a[NMB];
        #pragma unroll
        for (int mb = 0; mb < NMB; ++mb)
            a[mb] = *(const frag8*)(Al + rowbase[mb] + ((c8 ^ rx[mb]) << 3));
        #pragma unroll
        for (int tt = 0; tt < NTT; ++tt){
            frag8 b = *(const frag8*)(wbase + tt*16*wK + k0);
            #pragma unroll
            for (int mb = 0; mb < NMB; ++mb)
                acc[mb][tt] = mfma16(a[mb], b, acc[mb][tt]);
        }
    }
}

// Fused r+z pass over all NMB m-blocks (W rows 0..255 = r, 256..511 = z).
template<int NMB>
__device__ __forceinline__ void gemm_rz(facc4 (&accr)[NMB][2], facc4 (&accz)[NMB][2],
    const unsigned short* Al, const int mb0,
    const unsigned short* __restrict__ W, const int nrowr)
{
    const int lane = threadIdx.x & 63;
    const int r16  = lane & 15;
    const int q8   = (lane >> 4) << 3;
    int rowbase[NMB], rx[NMB];
    #pragma unroll
    for (int mb = 0; mb < NMB; ++mb){
        int row = (mb0 + mb)*16 + r16;
        rowbase[mb] = row * 256;
        rx[mb] = row & 7;
    }
    const unsigned short* wr = W + (size_t)(nrowr + r16) * 256 + q8;
    const unsigned short* wz = wr + (size_t)256 * 256;
    #pragma unroll 4
    for (int k0 = 0; k0 < 256; k0 += 32){
        const int c8 = (k0 + q8) >> 3;
        frag8 a[NMB];
        #pragma unroll
        for (int mb = 0; mb < NMB; ++mb)
            a[mb] = *(const frag8*)(Al + rowbase[mb] + ((c8 ^ rx[mb]) << 3));
        #pragma unroll
        for (int tt = 0; tt < 2; ++tt){
            frag8 br = *(const frag8*)(wr + tt*16*256 + k0);
            frag8 bz = *(const frag8*)(wz + tt*16*256 + k0);
            #pragma unroll
            for (int mb = 0; mb < NMB; ++mb){
                accr[mb][tt] = mfma16(a[mb], br, accr[mb][tt]);
                accz[mb][tt] = mfma16(a[mb], bz, accz[mb][tt]);
            }
        }
    }
}

// stage 64 rows x 256 cols of f32 (row stride sld) -> swizzled bf16 LDS (ld=256)
// 512 threads; non-temporal loads (pure stream)
__device__ __forceinline__ void stage_f32s(unsigned short* dst, const float* src, int sld){
    int t = threadIdx.x;
    #pragma unroll
    for (int it = 0; it < 4; ++it){
        int idx = it*512 + t;                  // 2048 chunks of 8 shorts
        int row = idx >> 5, ch = idx & 31;
        const f32x4* s = (const f32x4*)(src + (size_t)row*sld + (ch << 3));
        f32x4 a = __builtin_nontemporal_load(s);
        f32x4 b = __builtin_nontemporal_load(s + 1);
        uint4 o; o.x = pk2(a.x,a.y); o.y = pk2(a.z,a.w); o.z = pk2(b.x,b.y); o.w = pk2(b.z,b.w);
        *(uint4*)(dst + row*256 + ((ch ^ (row & 7)) << 3)) = o;
    }
}

// ---- weight f32->bf16 conversion (segments packed contiguously in ws) ----
__global__ void k_prep(const float* __restrict__ s0, const float* __restrict__ s1,
                       const float* __restrict__ s2, const float* __restrict__ s3,
                       const float* __restrict__ s4, const float* __restrict__ s5,
                       unsigned short* __restrict__ dst)
{
    int idx = (blockIdx.x*256 + threadIdx.x) * 4;   // 921600 elems total
    const float* src;
    if      (idx < 131072) src = s0 + idx;
    else if (idx < 327680) src = s1 + (idx - 131072);
    else if (idx < 524288) src = s2 + (idx - 327680);
    else if (idx < 720896) src = s3 + (idx - 524288);
    else if (idx < 917504) src = s4 + (idx - 720896);
    else                   src = s5 + (idx - 917504);
    float4 v = *(const float4*)src;
    uint2 o; o.x = pk2(v.x, v.y); o.y = pk2(v.z, v.w);
    *(uint2*)(dst + idx) = o;
}

// ---- barrier-free GRU over all 64 rows: gi from `gi`, gh from `gh`,
// h' -> `ob` (a buffer nobody reads until the post-GRU barrier).
// 8 waves x 32 cols; per wave NMB=4. NO __syncthreads inside.
template<bool WRITE_F32>
__device__ __forceinline__ void gru_nb(
    const unsigned short* gi, const unsigned short* gh, unsigned short* ob,
    const unsigned short* __restrict__ Wih, const unsigned short* __restrict__ Whh,
    const float* __restrict__ bih, const float* __restrict__ bhh,
    int base, float* __restrict__ out32)
{
    const int lane = threadIdx.x & 63, wv = threadIdx.x >> 6;
    const int r16 = lane & 15, q4 = (lane >> 4) << 2;
    unsigned rp[4][2][2], zp[4][2][2];
    // fused r+z pass (both operands)
    {
        facc4 accr[4][2], accz[4][2];
        zacc(&accr[0][0], 8);
        zacc(&accz[0][0], 8);
        gemm_rz<4>(accr, accz, gi, 0, Wih, wv*32);
        gemm_rz<4>(accr, accz, gh, 0, Whh, wv*32);
        #pragma unroll
        for (int tt = 0; tt < 2; ++tt){
            int col = wv*32 + tt*16 + r16;
            float bsr = bih[col] + bhh[col];
            float bsz = bih[256+col] + bhh[256+col];
            #pragma unroll
            for (int mb = 0; mb < 4; ++mb){
                rp[mb][tt][0] = pk2(sigm(accr[mb][tt][0]+bsr), sigm(accr[mb][tt][1]+bsr));
                rp[mb][tt][1] = pk2(sigm(accr[mb][tt][2]+bsr), sigm(accr[mb][tt][3]+bsr));
                zp[mb][tt][0] = pk2(sigm(accz[mb][tt][0]+bsz), sigm(accz[mb][tt][1]+bsz));
                zp[mb][tt][1] = pk2(sigm(accz[mb][tt][2]+bsz), sigm(accz[mb][tt][3]+bsz));
            }
        }
    }
    // n pass + epilogue (no barrier: writes go to ob, reads from gi/gh stay valid)
    {
        facc4 ai[4][2], ah[4][2];
        zacc(&ai[0][0], 8);
        zacc(&ah[0][0], 8);
        gemm_bt<4,2>(ai, gi, 256, 0, Wih, 512 + wv*32, 256, 256);
        gemm_bt<4,2>(ah, gh, 256, 0, Whh, 512 + wv*32, 256, 256);
        #pragma unroll
        for (int tt = 0; tt < 2; ++tt){
            int col = wv*32 + tt*16 + r16;
            float bi = bih[512+col], bh2 = bhh[512+col];
            #pragma unroll
            for (int mb = 0; mb < 4; ++mb){
                #pragma unroll
                for (int k = 0; k < 4; ++k){
                    int rloc = mb*16 + q4 + k;
                    float iv = ai[mb][tt][k] + bi;
                    float hv = ah[mb][tt][k] + bh2;
                    float r = bf2f((unsigned short)(rp[mb][tt][k>>1] >> ((k&1)*16)));
                    float z = bf2f((unsigned short)(zp[mb][tt][k>>1] >> ((k&1)*16)));
                    float n = tanh_(iv + r*hv);
                    float hprev = bf2f(gh[swz(rloc, col, 256)]);
                    float h = (1.f - z)*n + z*hprev;
                    if (WRITE_F32)
                        __builtin_nontemporal_store(h, &out32[(size_t)(base + rloc)*256 + col]);
                    ob[swz(rloc, col, 256)] = f2bf(h);
                }
            }
        }
    }
}

// c = (NB @ h) * invn per 32-agent group; h in hb, out -> cb. Barrier-free.
__device__ __forceinline__ void comm_c(const unsigned short* hb, unsigned short* cb,
                                       const unsigned short* NBl, const float* invl)
{
    const int lane = threadIdx.x & 63, wv = threadIdx.x >> 6;
    const int r16 = lane & 15, q8 = (lane >> 4) << 3, q4 = (lane >> 4) << 2;
    facc4 acc[4][2];
    zacc(&acc[0][0], 8);
    frag8 a[4];
    #pragma unroll
    for (int mb = 0; mb < 4; ++mb)
        a[mb] = *(const frag8*)(NBl + (mb*16 + r16)*40 + q8);
    #pragma unroll
    for (int tt = 0; tt < 2; ++tt){
        int col = wv*32 + tt*16 + r16;
        int cc = col >> 3, c7 = col & 7;
        frag8 b0, b1;
        #pragma unroll
        for (int j = 0; j < 8; ++j){
            int k0r = q8 + j;          // group 0 rows 0..31
            int k1r = 32 + q8 + j;     // group 1 rows 32..63
            b0[j] = (short)hb[k0r*256 + (((cc ^ (k0r & 7)) << 3) | c7)];
            b1[j] = (short)hb[k1r*256 + (((cc ^ (k1r & 7)) << 3) | c7)];
        }
        acc[0][tt] = mfma16(a[0], b0, acc[0][tt]);
        acc[1][tt] = mfma16(a[1], b0, acc[1][tt]);
        acc[2][tt] = mfma16(a[2], b1, acc[2][tt]);
        acc[3][tt] = mfma16(a[3], b1, acc[3][tt]);
    }
    #pragma unroll
    for (int mb = 0; mb < 4; ++mb){
        #pragma unroll
        for (int k = 0; k < 4; ++k){
            int rloc = mb*16 + q4 + k;
            float inv = invl[rloc];
            #pragma unroll
            for (int tt = 0; tt < 2; ++tt){
                int col = wv*32 + tt*16 + r16;
                cb[swz(rloc, col, 256)] = f2bf(acc[mb][tt][k] * inv);
            }
        }
    }
}

// ---- the whole pipeline, 64 rows (2 agent groups) per block, 512 threads ----
__global__ __launch_bounds__(512) void k_fused(
    const float* __restrict__ inputs, const float* __restrict__ h0,
    const unsigned short* __restrict__ W1c, const float* __restrict__ b1,
    const unsigned short* __restrict__ rWih, const unsigned short* __restrict__ rWhh,
    const float* __restrict__ rbih, const float* __restrict__ rbhh,
    const unsigned short* __restrict__ cWih, const unsigned short* __restrict__ cWhh,
    const float* __restrict__ cbih, const float* __restrict__ cbhh,
    const unsigned short* __restrict__ W2c, const float* __restrict__ b2,
    float* __restrict__ qout, float* __restrict__ hrnn)
{
    __shared__ unsigned short Abuf[64*256];  // 32 KB
    __shared__ unsigned short Bbuf[64*256];  // 32 KB
    __shared__ unsigned short Cbuf[64*256];  // 32 KB
    __shared__ unsigned short NBl[64*40];    // 5 KB
    __shared__ float invl[64];
    const int base = blockIdx.x * 64;
    const int lane = threadIdx.x & 63, wv = threadIdx.x >> 6;
    const int r16 = lane & 15, q8 = (lane >> 4) << 3, q4 = (lane >> 4) << 2;

    // h0 staging issued FIRST: B is untouched until the RNN GRU, so these
    // NT loads + LDS writes hide under the entire X phase (syncs in between).
    stage_f32s(Bbuf, h0 + (size_t)base*256, 256);

    // ================= phase X: x = relu(inp @ W1^T + b1) -> A =================
    {
        facc4 acc[4][2];
        zacc(&acc[0][0], 8);
        // K-half 1 (input cols 0..255) staged in C
        stage_f32s(Cbuf, inputs + (size_t)base*512, 512);
        __syncthreads();
        gemm_bt<4,2>(acc, Cbuf, 256, 0, W1c, wv*32, 256, 512);
        __syncthreads();                            // all reads of C done
        // K-half 2 (input cols 256..511)
        stage_f32s(Cbuf, inputs + (size_t)base*512 + 256, 512);
        __syncthreads();
        // neighbor extraction: global cols 260+8k -> local col 4+8k -> chunk k, sub 4
        if (threadIdx.x < 64){
            int row = threadIdx.x;
            int gr = base + row;
            int i = gr & 31;
            int rx = row & 7;
            unsigned short* nbrow = NBl + row*40;
            float s = 0.f;
            nbrow[i] = 0;
            #pragma unroll
            for (int k = 0; k < 31; ++k){
                unsigned short v = Cbuf[row*256 + (((k ^ rx) << 3) | 4)];
                s += bf2f(v);
                nbrow[k + (k >= i)] = v;
            }
            invl[row] = 1.0f / s;
        }
        gemm_bt<4,2>(acc, Cbuf, 256, 0, W1c + 256, wv*32, 256, 512);
        // write X -> A (A untouched so far; no barrier needed before writes)
        #pragma unroll
        for (int tt = 0; tt < 2; ++tt){
            int col = wv*32 + tt*16 + r16;
            float bias = b1[col];
            #pragma unroll
            for (int mb = 0; mb < 4; ++mb){
                #pragma unroll
                for (int k = 0; k < 4; ++k){
                    float v = fmaxf(acc[mb][tt][k] + bias, 0.f);
                    Abuf[swz(mb*16 + q4 + k, col, 256)] = f2bf(v);
                }
            }
        }
    }
    __syncthreads();        // X in A complete; h0 in B complete; C reads done

    // ================= rnn GRU: h1 = GRU(X, h0) -> C (barrier-free) ==========
    gru_nb<true>(Abuf, Bbuf, Cbuf, rWih, rWhh, rbih, rbhh, base, hrnn);
    __syncthreads();        // h1 in C; A,B now dead

    // ================= 4 comm steps, 3-buffer rotation =================
    unsigned short *hb = Cbuf, *cb = Abuf, *ob = Bbuf;
    #pragma unroll 1
    for (int step = 0; step < 4; ++step){
        comm_c(hb, cb, NBl, invl);      // c -> cb (dead buffer)
        __syncthreads();                // cb ready for all waves
        gru_nb<false>(hb, cb, ob, cWih, cWhh, cbih, cbhh, base, nullptr);
        __syncthreads();                // h' in ob; hb,cb now dead
        unsigned short* t = hb; hb = ob; ob = cb; cb = t;   // (h,c,o) <- (o,h,c)
    }

    // ================= q = h @ W2^T + b2 (N=16, one n-tile) =================
    if (wv < 4){
        facc4 qa = (facc4){0.f,0.f,0.f,0.f};
        int rowl = wv*16 + r16;
        const int rb = rowl*256, rx = rowl & 7;
        const unsigned short* brow = W2c + (size_t)r16*256 + q8;
        #pragma unroll
        for (int k0 = 0; k0 < 256; k0 += 32){
            int c8 = (k0 + q8) >> 3;
            frag8 af = *(const frag8*)(hb + rb + ((c8 ^ rx) << 3));
            frag8 bf = *(const frag8*)(brow + k0);
            qa = mfma16(af, bf, qa);
        }
        float bias = b2[r16];
        #pragma unroll
        for (int k = 0; k < 4; ++k)
            __builtin_nontemporal_store(qa[k] + bias,
                &qout[(size_t)(base + wv*16 + q4 + k)*16 + r16]);
    }
}

extern "C" void kernel_launch(void* const* d_in, const int* in_sizes, int n_in,
                              void* d_out, int out_size, void* d_ws, size_t ws_size,
                              hipStream_t stream)
{
    const float* inputs = (const float*)d_in[0];
    const float* h0     = (const float*)d_in[1];
    const float* W1     = (const float*)d_in[2];
    const float* b1     = (const float*)d_in[3];
    const float* rWih   = (const float*)d_in[4];
    const float* rWhh   = (const float*)d_in[5];
    const float* rbih   = (const float*)d_in[6];
    const float* rbhh   = (const float*)d_in[7];
    const float* cWih   = (const float*)d_in[8];
    const float* cWhh   = (const float*)d_in[9];
    const float* cbih   = (const float*)d_in[10];
    const float* cbhh   = (const float*)d_in[11];
    const float* W2     = (const float*)d_in[12];
    const float* b2     = (const float*)d_in[13];

    float* qout = (float*)d_out;                    // 65536 x 16
    float* hrnn = qout + (size_t)65536*16;          // 65536 x 256

    // ws: bf16 weights only (921600 elems), segments packed contiguously
    unsigned short* wsb   = (unsigned short*)d_ws;
    unsigned short* W1c   = wsb;
    unsigned short* rWihc = wsb + 131072;
    unsigned short* rWhhc = wsb + 327680;
    unsigned short* cWihc = wsb + 524288;
    unsigned short* cWhhc = wsb + 720896;
    unsigned short* W2c   = wsb + 917504;

    k_prep <<<900, dim3(256), 0, stream>>>(W1, rWih, rWhh, cWih, cWhh, W2, wsb);
    k_fused<<<1024, dim3(512), 0, stream>>>(inputs, h0, W1c, b1,
                                            rWihc, rWhhc, rbih, rbhh,
                                            cWihc, cWhhc, cbih, cbhh,
                                            W2c, b2, qout, hrnn);
}